// Round 9
// baseline (184.552 us; speedup 1.0000x reference)
//
#include <hip/hip_runtime.h>
#include <hip/hip_bf16.h>
#include <math.h>

typedef __attribute__((ext_vector_type(8))) short short8;
typedef __attribute__((ext_vector_type(4))) float floatx4;

#define MARGIN_C    0.09f
#define ONE_M_EPS   0.99999f
#define NCLS        64
#define MEMSTRIDE   256

__device__ __forceinline__ unsigned short f2bf(float f) {
    unsigned u = __float_as_uint(f);
    u += 0x7fffu + ((u >> 16) & 1u);
    return (unsigned short)(u >> 16);
}
__device__ __forceinline__ float bf2f(unsigned short v) {
    return __uint_as_float(((unsigned)v) << 16);
}
// order-preserving float<->uint key for atomicMax on floats
__device__ __forceinline__ unsigned fkey(float f) {
    unsigned u = __float_as_uint(f);
    return (u >> 31) ? ~u : (u | 0x80000000u);
}
__device__ __forceinline__ float fdec(unsigned k) {
    return __uint_as_float((k >> 31) ? (k & 0x7fffffffu) : ~k);
}

// ---------- fused: fp32->bf16 cvt + stat zeroing + out zeroing + member lists
__global__ __launch_bounds__(256) void cvt_build(const float* __restrict__ in,
                                                 unsigned short* __restrict__ out,
                                                 float* __restrict__ statz,   // negsum+negmax
                                                 const int* __restrict__ labels,
                                                 int* __restrict__ members,
                                                 int* __restrict__ classCount,
                                                 float* __restrict__ loss_out,
                                                 int n4, int nz4, int ncvt, int Bn) {
    __shared__ int cnt;
    const int bid = blockIdx.x;
    const int t = threadIdx.x;
    if (bid < ncvt) {
        int i = bid * 256 + t;
        if (bid == 0 && t == 0) loss_out[0] = 0.0f;
        if (i < nz4) ((float4*)statz)[i] = make_float4(0.f, 0.f, 0.f, 0.f);
        if (i >= n4) return;
        float4 v = ((const float4*)in)[i];
        ushort4 o;
        o.x = f2bf(v.x); o.y = f2bf(v.y); o.z = f2bf(v.z); o.w = f2bf(v.w);
        ((ushort4*)out)[i] = o;
    } else {
        const int c = bid - ncvt;
        if (t == 0) cnt = 0;
        __syncthreads();
        for (int j = t; j < Bn; j += 256) {
            if (labels[j] == c) {
                int p = atomicAdd(&cnt, 1);
                if (p < MEMSTRIDE) members[c * MEMSTRIDE + p] = j;
            }
        }
        __syncthreads();
        if (t == 0) classCount[c] = (cnt < MEMSTRIDE) ? cnt : MEMSTRIDE;
    }
}

// ---------- GEMM (lower-tri tiles), LDS-FREE K-loop + fused epilogue --------
// C = F * F^T with F row-major => every MFMA A/B fragment is a contiguous
// 16B row-chunk of fb: A-frag(i,k) = fb[by*128+wr*64+i*16+m16][k + quad*8..],
// B-frag(j,k) = fb[bx*128+wc*64+j*16+m16][k + quad*8..]. Load fragments
// directly global->VGPR (L1/L2-resident, fb = 8.4MB), no staging, no barriers.
// 4-deep rotation gives ~230cyc prefetch distance per wave.
#define LOADF(Aset, Bset, ko) {                                               \
    const int _k = (ko);                                                      \
    _Pragma("unroll")                                                         \
    for (int i = 0; i < 4; i++) Aset[i] = *(const short8*)(pA + (size_t)i * 16 * Dn + _k); \
    _Pragma("unroll")                                                         \
    for (int j = 0; j < 4; j++) Bset[j] = *(const short8*)(pB + (size_t)j * 16 * Dn + _k); }

#define MM(Aset, Bset) {                                                      \
    _Pragma("unroll")                                                         \
    for (int i = 0; i < 4; i++)                                               \
        _Pragma("unroll")                                                     \
        for (int j = 0; j < 4; j++)                                           \
            acc[i][j] = __builtin_amdgcn_mfma_f32_16x16x32_bf16(Aset[i], Bset[j], acc[i][j], 0, 0, 0); }

__global__ __launch_bounds__(256, 2) void gemm_fused(const unsigned short* __restrict__ fb,
                                                     const int* __restrict__ labels,
                                                     float* __restrict__ negsum,
                                                     unsigned* __restrict__ negmax,
                                                     unsigned short* __restrict__ pairsim,
                                                     int Bn, int Dn) {
    __shared__ int Lrow[128], Lcol[128];

    const int bid = blockIdx.x;
    int by = (int)((sqrtf(8.f * (float)bid + 1.f) - 1.f) * 0.5f);
    while ((by + 1) * (by + 2) / 2 <= bid) by++;
    while (by * (by + 1) / 2 > bid) by--;
    const int bx = bid - by * (by + 1) / 2;

    const int t = threadIdx.x;
    const int wave = t >> 6, lane = t & 63;
    const int wr = wave >> 1, wc = wave & 1;
    const int quad = lane >> 4, m16 = lane & 15;

    if (t < 128) Lrow[t] = labels[by * 128 + t];
    else         Lcol[t - 128] = labels[bx * 128 + (t - 128)];

    const unsigned short* pA = fb + (size_t)(by * 128 + wr * 64 + m16) * Dn + quad * 8;
    const unsigned short* pB = fb + (size_t)(bx * 128 + wc * 64 + m16) * Dn + quad * 8;

    floatx4 acc[4][4];
#pragma unroll
    for (int i = 0; i < 4; i++)
#pragma unroll
        for (int j = 0; j < 4; j++) acc[i][j] = (floatx4){0.f, 0.f, 0.f, 0.f};

    short8 A0[4], B0[4], A1[4], B1[4], A2[4], B2[4], A3[4], B3[4];
    LOADF(A0, B0, 0);
    LOADF(A1, B1, 32);
    LOADF(A2, B2, 64);

    const int kmax = Dn - 32;
    for (int c = 0; c < Dn; c += 128) {
        int k3 = c + 96;            // always < Dn for Dn % 128 == 0
        int k4 = c + 128; k4 = (k4 < kmax) ? k4 : kmax;   // clamped redundant
        int k5 = c + 160; k5 = (k5 < kmax) ? k5 : kmax;   // prefetches on the
        int k6 = c + 192; k6 = (k6 < kmax) ? k6 : kmax;   // last iteration
        LOADF(A3, B3, k3);
        MM(A0, B0);
        LOADF(A0, B0, k4);
        MM(A1, B1);
        LOADF(A1, B1, k5);
        MM(A2, B2);
        LOADF(A2, B2, k6);
        MM(A3, B3);
    }
    __syncthreads();   // Lrow/Lcol visibility (writes above, first read below)

    // ----- single-pass epilogue (C/D: col = m16 + j*16, row = quad*4+r + i*16)
    const bool offd = (bx != by);
    int cl[4], gc[4];
#pragma unroll
    for (int j = 0; j < 4; j++) {
        cl[j] = Lcol[wc * 64 + j * 16 + m16];
        gc[j] = bx * 128 + wc * 64 + j * 16 + m16;
    }

    float nsm[4] = {0.f, 0.f, 0.f, 0.f};
    float nmm[4] = {-INFINITY, -INFINITY, -INFINITY, -INFINITY};

#pragma unroll
    for (int i = 0; i < 4; i++) {
#pragma unroll
        for (int r = 0; r < 4; r++) {
            const int rowl = wr * 64 + i * 16 + quad * 4 + r;
            const int rl = Lrow[rowl];
            const int gr = by * 128 + rowl;
            float ns = 0.f, nm = -INFINITY;
#pragma unroll
            for (int j = 0; j < 4; j++) {
                const float s = acc[i][j][r];
                if (cl[j] != rl) {
                    const float e = __expf(40.f * s);
                    ns += e;
                    nm = fmaxf(nm, s);
                    nsm[j] += e;
                    nmm[j] = fmaxf(nmm[j], s);
                } else if ((gr != gc[j]) & (s < ONE_M_EPS)) {
                    const unsigned short v = f2bf(s);
                    pairsim[(size_t)gr * Bn + gc[j]] = v;
                    if (offd) pairsim[(size_t)gc[j] * Bn + gr] = v;
                }
            }
#pragma unroll
            for (int o = 8; o; o >>= 1) {
                ns += __shfl_down(ns, o, 64);
                nm = fmaxf(nm, __shfl_down(nm, o, 64));
            }
            if (m16 == 0) {
                atomicAdd(negsum + gr, ns);
                atomicMax(negmax + gr, fkey(nm));
            }
        }
    }
    if (offd) {   // mirror negative stats: this tile's cols are rows bx*128..
#pragma unroll
        for (int j = 0; j < 4; j++) {
            float v = nsm[j], m = nmm[j];
            v += __shfl_down(v, 16, 64);
            m = fmaxf(m, __shfl_down(m, 16, 64));
            v += __shfl_down(v, 32, 64);
            m = fmaxf(m, __shfl_down(m, 32, 64));
            if (quad == 0) {
                atomicAdd(negsum + gc[j], v);
                atomicMax(negmax + gc[j], fkey(m));
            }
        }
    }
}

// ---------- positives + per-row loss + mean, merged (16 rows/block) ---------
__global__ __launch_bounds__(256) void pos_final(const unsigned short* __restrict__ pairsim,
                                                 const int* __restrict__ labels,
                                                 const int* __restrict__ members,
                                                 const int* __restrict__ classCount,
                                                 const unsigned* __restrict__ negmax,
                                                 const float* __restrict__ negsum,
                                                 float* __restrict__ out, int Bn) {
    __shared__ float part[4];
    const int t = threadIdx.x;
    const int wave = t >> 6, lane = t & 63;
    float wacc = 0.f;
#pragma unroll
    for (int rr = 0; rr < 4; rr++) {
        const int r = blockIdx.x * 16 + wave * 4 + rr;
        if (r >= Bn) break;
        const int lab = labels[r];
        const int n = classCount[lab];
        const int base = lab * MEMSTRIDE;
        const float mx = fdec(negmax[r]);
        const unsigned short* prow = pairsim + (size_t)r * Bn;

        float ps = 0.f, pc = 0.f;
        for (int j = lane; j < n; j += 64) {
            const int m = members[base + j];
            if (m != r) {
                const float s = bf2f(prow[m]);
                if ((s - MARGIN_C) < mx) {
                    ps += __expf(-2.f * s);
                    pc += 1.f;
                }
            }
        }
#pragma unroll
        for (int o = 32; o; o >>= 1) {
            ps += __shfl_down(ps, o, 64);
            pc += __shfl_down(pc, o, 64);
        }
        if (lane == 0) {
            const int nneg = Bn - n;
            if (nneg >= 1 && pc >= 0.5f) {
                float pl = 0.5f * logf((ps + expf(-2.f * 0.501f)) / (pc + 1.f));
                float nl = (1.f / 40.f) * logf((negsum[r] + expf(40.f * 0.531f)) / ((float)nneg + 1.f));
                wacc += logf(5.33f + expf(pl + nl));
            }
        }
    }
    if (lane == 0) part[wave] = wacc;
    __syncthreads();
    if (t == 0) {
        atomicAdd(out, (part[0] + part[1] + part[2] + part[3]) / (float)Bn);
    }
}

extern "C" void kernel_launch(void* const* d_in, const int* in_sizes, int n_in,
                              void* d_out, int out_size, void* d_ws, size_t ws_size,
                              hipStream_t stream) {
    const float* feats = (const float*)d_in[0];
    const int* labels  = (const int*)d_in[1];
    float* out = (float*)d_out;

    const int Bn = in_sizes[1];           // 4096
    const int Dn = in_sizes[0] / Bn;      // 1024

    unsigned short* fb = (unsigned short*)d_ws;                 // bf16 feats [Bn][Dn]
    float* stats    = (float*)(fb + (size_t)Bn * Dn);
    float* negsum   = stats;                                    // [Bn]
    unsigned* negmax = (unsigned*)(stats + Bn);                 // [Bn] keyed
    int* classCount = (int*)(stats + 2 * Bn);                   // [NCLS]
    int* members    = classCount + NCLS;                        // [NCLS][MEMSTRIDE]
    unsigned short* pairsim = (unsigned short*)(members + NCLS * MEMSTRIDE); // [Bn][Bn]

    const int n4   = (Bn * Dn) / 4;
    const int nz4  = (2 * Bn) / 4;        // zero negsum+negmax
    const int ncvt = (n4 + 255) / 256;
    cvt_build<<<ncvt + NCLS, 256, 0, stream>>>(feats, fb, stats, labels,
                                               members, classCount, out,
                                               n4, nz4, ncvt, Bn);

    const int nt = Bn / 128;
    const int ntri = nt * (nt + 1) / 2;   // 528
    gemm_fused<<<ntri, 256, 0, stream>>>(fb, labels, negsum, negmax, pairsim, Bn, Dn);

    pos_final<<<(Bn + 15) / 16, 256, 0, stream>>>(pairsim, labels, members, classCount,
                                                  negmax, negsum, out, Bn);
}

// Round 10
// 119.305 us; speedup vs baseline: 1.5469x; 1.5469x over previous
//
#include <hip/hip_runtime.h>
#include <hip/hip_bf16.h>
#include <math.h>

typedef __attribute__((ext_vector_type(8))) short short8;
typedef __attribute__((ext_vector_type(4))) float floatx4;

#define MARGIN_C    0.09f
#define ONE_M_EPS   0.99999f
#define NCLS        64
#define MEMSTRIDE   256

__device__ __forceinline__ unsigned short f2bf(float f) {
    unsigned u = __float_as_uint(f);
    u += 0x7fffu + ((u >> 16) & 1u);
    return (unsigned short)(u >> 16);
}
__device__ __forceinline__ float bf2f(unsigned short v) {
    return __uint_as_float(((unsigned)v) << 16);
}
// order-preserving float<->uint key for atomicMax on floats
__device__ __forceinline__ unsigned fkey(float f) {
    unsigned u = __float_as_uint(f);
    return (u >> 31) ? ~u : (u | 0x80000000u);
}
__device__ __forceinline__ float fdec(unsigned k) {
    return __uint_as_float((k >> 31) ? (k & 0x7fffffffu) : ~k);
}
__device__ __forceinline__ void gld16(const void* g, void* l) {
    __builtin_amdgcn_global_load_lds(
        (const __attribute__((address_space(1))) void*)g,
        (__attribute__((address_space(3))) void*)l, 16, 0, 0);
}

// ---------- fused: fp32->bf16 cvt + stat zeroing + out zeroing + member lists
__global__ __launch_bounds__(256) void cvt_build(const float* __restrict__ in,
                                                 unsigned short* __restrict__ out,
                                                 float* __restrict__ statz,   // negsum+negmax
                                                 const int* __restrict__ labels,
                                                 int* __restrict__ members,
                                                 int* __restrict__ classCount,
                                                 float* __restrict__ loss_out,
                                                 int n4, int nz4, int ncvt, int Bn) {
    __shared__ int cnt;
    const int bid = blockIdx.x;
    const int t = threadIdx.x;
    if (bid < ncvt) {
        int i = bid * 256 + t;
        if (bid == 0 && t == 0) loss_out[0] = 0.0f;
        if (i < nz4) ((float4*)statz)[i] = make_float4(0.f, 0.f, 0.f, 0.f);
        if (i >= n4) return;
        float4 v = ((const float4*)in)[i];
        ushort4 o;
        o.x = f2bf(v.x); o.y = f2bf(v.y); o.z = f2bf(v.z); o.w = f2bf(v.w);
        ((ushort4*)out)[i] = o;
    } else {
        const int c = bid - ncvt;
        if (t == 0) cnt = 0;
        __syncthreads();
        for (int j = t; j < Bn; j += 256) {
            if (labels[j] == c) {
                int p = atomicAdd(&cnt, 1);
                if (p < MEMSTRIDE) members[c * MEMSTRIDE + p] = j;
            }
        }
        __syncthreads();
        if (t == 0) classCount[c] = (cnt < MEMSTRIDE) ? cnt : MEMSTRIDE;
    }
}

// ---------- GEMM (lower-tri tiles) + fused neg stats + pos scatter ----------
// 128x128 tile, BK=32, DOUBLE-BUFFERED global_load_lds staging: the load IS
// the LDS write (no VGPR round-trip, nothing for the compiler to sink), issued
// at stage top; the vmcnt(0) drain at __syncthreads comes a full compute
// stage (~1.2Kcyc) later -> L2 latency hidden by construction. One barrier
// per stage. 32KB LDS. Diagonal tiles skip B staging (B == A).
__global__ __launch_bounds__(256, 2) void gemm_fused(const unsigned short* __restrict__ fb,
                                                     const int* __restrict__ labels,
                                                     float* __restrict__ negsum,
                                                     unsigned* __restrict__ negmax,
                                                     unsigned short* __restrict__ pairsim,
                                                     int Bn, int Dn) {
    __shared__ __align__(16) unsigned short As[2][4096];   // 16KB
    __shared__ __align__(16) unsigned short Bs[2][4096];   // 16KB
    __shared__ int Lrow[128], Lcol[128];

    const int bid = blockIdx.x;
    int by = (int)((sqrtf(8.f * (float)bid + 1.f) - 1.f) * 0.5f);
    while ((by + 1) * (by + 2) / 2 <= bid) by++;
    while (by * (by + 1) / 2 > bid) by--;
    const int bx = bid - by * (by + 1) / 2;
    const bool diag = (bx == by);

    const int t = threadIdx.x;
    const int wave = t >> 6, lane = t & 63;
    const int wr = wave >> 1, wc = wave & 1;
    const int quad = lane >> 4, m16 = lane & 15;

    if (t < 128) Lrow[t] = labels[by * 128 + t];
    else         Lcol[t - 128] = labels[bx * 128 + (t - 128)];

    // staging: thread t -> LDS offset t*16B (rows lr, lr+64), k-chunk rotated.
    // gld_lds lane->LDS mapping is base + lane*16 (wave-uniform base) == t*16. OK.
    const int lr = t >> 2, slot = t & 3, kf = (slot + lr) & 3;
    const unsigned short* gA0 = fb + (size_t)(by * 128 + lr) * Dn + kf * 8;
    const unsigned short* gB0 = fb + (size_t)(bx * 128 + lr) * Dn + kf * 8;
    const unsigned short* gA1 = gA0 + (size_t)64 * Dn;
    const unsigned short* gB1 = gB0 + (size_t)64 * Dn;
    const int lb = t * 8;   // shorts

    floatx4 acc[4][4];
#pragma unroll
    for (int i = 0; i < 4; i++)
#pragma unroll
        for (int j = 0; j < 4; j++) acc[i][j] = (floatx4){0.f, 0.f, 0.f, 0.f};

    // fragment reads: row stride 32 shorts; chunk quad at slot (quad-m16)&3
    const int fragA = (wr * 64 + m16) * 32 + ((quad - m16) & 3) * 8;
    const int fragB = (wc * 64 + m16) * 32 + ((quad - m16) & 3) * 8;

    const int NS = Dn / 32;   // 32 stages

    // prologue: stage 0 into buf 0
    gld16(gA0, &As[0][lb]);
    gld16(gA1, &As[0][2048 + lb]);
    if (!diag) {
        gld16(gB0, &Bs[0][lb]);
        gld16(gB1, &Bs[0][2048 + lb]);
    }
    __syncthreads();

    for (int s = 0; s < NS; s++) {
        // issue next-stage DMA first (into the other buffer)
        if (s + 1 < NS) {
            const int ko = (s + 1) * 32;
            const int nb = (s + 1) & 1;
            gld16(gA0 + ko, &As[nb][lb]);
            gld16(gA1 + ko, &As[nb][2048 + lb]);
            if (!diag) {
                gld16(gB0 + ko, &Bs[nb][lb]);
                gld16(gB1 + ko, &Bs[nb][2048 + lb]);
            }
        }
        __builtin_amdgcn_sched_barrier(0);   // pin DMA issue before compute

        const unsigned short* as_ = As[s & 1];
        const unsigned short* bs_ = diag ? as_ : Bs[s & 1];
        short8 af[4], bfr[4];
#pragma unroll
        for (int i = 0; i < 4; i++) af[i]  = *(const short8*)(as_ + fragA + i * 512);
#pragma unroll
        for (int i = 0; i < 4; i++) bfr[i] = *(const short8*)(bs_ + fragB + i * 512);
#pragma unroll
        for (int i = 0; i < 4; i++)
#pragma unroll
            for (int j = 0; j < 4; j++)
                acc[i][j] = __builtin_amdgcn_mfma_f32_16x16x32_bf16(af[i], bfr[j], acc[i][j], 0, 0, 0);
        __syncthreads();   // drains vmcnt(0): next-stage DMA (issued ~1.2Kcyc ago) done
    }

    // ----- single-pass epilogue (C/D: col = m16 + j*16, row = quad*4+r + i*16)
    const bool offd = !diag;
    int cl[4], gc[4];
#pragma unroll
    for (int j = 0; j < 4; j++) {
        cl[j] = Lcol[wc * 64 + j * 16 + m16];
        gc[j] = bx * 128 + wc * 64 + j * 16 + m16;
    }

    float nsm[4] = {0.f, 0.f, 0.f, 0.f};
    float nmm[4] = {-INFINITY, -INFINITY, -INFINITY, -INFINITY};

#pragma unroll
    for (int i = 0; i < 4; i++) {
#pragma unroll
        for (int r = 0; r < 4; r++) {
            const int rowl = wr * 64 + i * 16 + quad * 4 + r;
            const int rl = Lrow[rowl];
            const int gr = by * 128 + rowl;
            float ns = 0.f, nm = -INFINITY;
#pragma unroll
            for (int j = 0; j < 4; j++) {
                const float s = acc[i][j][r];
                if (cl[j] != rl) {
                    const float e = __expf(40.f * s);
                    ns += e;
                    nm = fmaxf(nm, s);
                    nsm[j] += e;
                    nmm[j] = fmaxf(nmm[j], s);
                } else if ((gr != gc[j]) & (s < ONE_M_EPS)) {
                    const unsigned short v = f2bf(s);
                    pairsim[(size_t)gr * Bn + gc[j]] = v;
                    if (offd) pairsim[(size_t)gc[j] * Bn + gr] = v;
                }
            }
#pragma unroll
            for (int o = 8; o; o >>= 1) {
                ns += __shfl_down(ns, o, 64);
                nm = fmaxf(nm, __shfl_down(nm, o, 64));
            }
            if (m16 == 0) {
                atomicAdd(negsum + gr, ns);
                atomicMax(negmax + gr, fkey(nm));
            }
        }
    }
    if (offd) {   // mirror negative stats: this tile's cols are rows bx*128..
#pragma unroll
        for (int j = 0; j < 4; j++) {
            float v = nsm[j], m = nmm[j];
            v += __shfl_down(v, 16, 64);
            m = fmaxf(m, __shfl_down(m, 16, 64));
            v += __shfl_down(v, 32, 64);
            m = fmaxf(m, __shfl_down(m, 32, 64));
            if (quad == 0) {
                atomicAdd(negsum + gc[j], v);
                atomicMax(negmax + gc[j], fkey(m));
            }
        }
    }
}

// ---------- positives + per-row loss + mean, merged (16 rows/block) ---------
__global__ __launch_bounds__(256) void pos_final(const unsigned short* __restrict__ pairsim,
                                                 const int* __restrict__ labels,
                                                 const int* __restrict__ members,
                                                 const int* __restrict__ classCount,
                                                 const unsigned* __restrict__ negmax,
                                                 const float* __restrict__ negsum,
                                                 float* __restrict__ out, int Bn) {
    __shared__ float part[4];
    const int t = threadIdx.x;
    const int wave = t >> 6, lane = t & 63;
    float wacc = 0.f;
#pragma unroll
    for (int rr = 0; rr < 4; rr++) {
        const int r = blockIdx.x * 16 + wave * 4 + rr;
        if (r >= Bn) break;
        const int lab = labels[r];
        const int n = classCount[lab];
        const int base = lab * MEMSTRIDE;
        const float mx = fdec(negmax[r]);
        const unsigned short* prow = pairsim + (size_t)r * Bn;

        float ps = 0.f, pc = 0.f;
        for (int j = lane; j < n; j += 64) {
            const int m = members[base + j];
            if (m != r) {
                const float s = bf2f(prow[m]);
                if ((s - MARGIN_C) < mx) {
                    ps += __expf(-2.f * s);
                    pc += 1.f;
                }
            }
        }
#pragma unroll
        for (int o = 32; o; o >>= 1) {
            ps += __shfl_down(ps, o, 64);
            pc += __shfl_down(pc, o, 64);
        }
        if (lane == 0) {
            const int nneg = Bn - n;
            if (nneg >= 1 && pc >= 0.5f) {
                float pl = 0.5f * logf((ps + expf(-2.f * 0.501f)) / (pc + 1.f));
                float nl = (1.f / 40.f) * logf((negsum[r] + expf(40.f * 0.531f)) / ((float)nneg + 1.f));
                wacc += logf(5.33f + expf(pl + nl));
            }
        }
    }
    if (lane == 0) part[wave] = wacc;
    __syncthreads();
    if (t == 0) {
        atomicAdd(out, (part[0] + part[1] + part[2] + part[3]) / (float)Bn);
    }
}

extern "C" void kernel_launch(void* const* d_in, const int* in_sizes, int n_in,
                              void* d_out, int out_size, void* d_ws, size_t ws_size,
                              hipStream_t stream) {
    const float* feats = (const float*)d_in[0];
    const int* labels  = (const int*)d_in[1];
    float* out = (float*)d_out;

    const int Bn = in_sizes[1];           // 4096
    const int Dn = in_sizes[0] / Bn;      // 1024

    unsigned short* fb = (unsigned short*)d_ws;                 // bf16 feats [Bn][Dn]
    float* stats    = (float*)(fb + (size_t)Bn * Dn);
    float* negsum   = stats;                                    // [Bn]
    unsigned* negmax = (unsigned*)(stats + Bn);                 // [Bn] keyed
    int* classCount = (int*)(stats + 2 * Bn);                   // [NCLS]
    int* members    = classCount + NCLS;                        // [NCLS][MEMSTRIDE]
    unsigned short* pairsim = (unsigned short*)(members + NCLS * MEMSTRIDE); // [Bn][Bn]

    const int n4   = (Bn * Dn) / 4;
    const int nz4  = (2 * Bn) / 4;        // zero negsum+negmax
    const int ncvt = (n4 + 255) / 256;
    cvt_build<<<ncvt + NCLS, 256, 0, stream>>>(feats, fb, stats, labels,
                                               members, classCount, out,
                                               n4, nz4, ncvt, Bn);

    const int nt = Bn / 128;
    const int ntri = nt * (nt + 1) / 2;   // 528
    gemm_fused<<<ntri, 256, 0, stream>>>(fb, labels, negsum, negmax, pairsim, Bn, Dn);

    pos_final<<<(Bn + 15) / 16, 256, 0, stream>>>(pairsim, labels, members, classCount,
                                                  negmax, negsum, out, Bn);
}